// Round 8
// baseline (666.283 us; speedup 1.0000x reference)
//
#include <hip/hip_runtime.h>
#include <hip/hip_bf16.h>

#define B_SZ 4
#define L_SZ 512
#define D_MODEL 256
#define D_INNER 512
#define D_STATE 16
#define DT_RANK 16
#define N_LAYERS 6
#define BL (B_SZ * L_SZ)   // 2048 token rows

typedef __bf16 bf16_t;
typedef __bf16 bf16x8 __attribute__((ext_vector_type(8)));
typedef __bf16 bf16x4 __attribute__((ext_vector_type(4)));
typedef float  f32x4  __attribute__((ext_vector_type(4)));

// All-reduce over the 16-lane DPP row via rotate-add.
__device__ __forceinline__ float row_allreduce16(float x)
{
    int v;
    v = __builtin_amdgcn_mov_dpp(__float_as_int(x), 0x121, 0xf, 0xf, true);
    x += __int_as_float(v);
    v = __builtin_amdgcn_mov_dpp(__float_as_int(x), 0x122, 0xf, 0xf, true);
    x += __int_as_float(v);
    v = __builtin_amdgcn_mov_dpp(__float_as_int(x), 0x124, 0xf, 0xf, true);
    x += __int_as_float(v);
    v = __builtin_amdgcn_mov_dpp(__float_as_int(x), 0x128, 0xf, 0xf, true);
    x += __int_as_float(v);
    return x;
}

// ---------------------------------------------------------------------------
// fp32 -> bf16 cast of the three weight tensors in one dispatch.
// ---------------------------------------------------------------------------
__global__ __launch_bounds__(256) void cast3_kernel(
    const float* __restrict__ s0, const float* __restrict__ s1,
    const float* __restrict__ s2, bf16_t* __restrict__ dst,
    int n0, int n1, int n2)
{
    int i = blockIdx.x * 256 + threadIdx.x;
    const float* s; int off;
    if (i < n0)            { s = s0; off = i; }
    else if (i < n0 + n1)  { s = s1; off = i - n0; }
    else if (i < n0+n1+n2) { s = s2; off = i - n0 - n1; }
    else return;
    const float4 v = *(const float4*)(s + (size_t)off * 4);
    bf16x4 o;
    o[0] = (bf16_t)v.x; o[1] = (bf16_t)v.y;
    o[2] = (bf16_t)v.z; o[3] = (bf16_t)v.w;
    *(bf16x4*)(dst + (size_t)i * 4) = o;
}

// ---------------------------------------------------------------------------
// RMSNorm -> bf16 output. Layer 0 only (others fused into gemm_wout_norm).
// ---------------------------------------------------------------------------
__global__ __launch_bounds__(256) void rmsnorm_kernel(
    const float* __restrict__ x, const float* __restrict__ w,
    bf16_t* __restrict__ o)
{
    int row  = blockIdx.x * 4 + (threadIdx.x >> 6);
    int lane = threadIdx.x & 63;
    const float4 v = *(const float4*)(x + (size_t)row * D_MODEL + lane * 4);
    float ss = v.x * v.x + v.y * v.y + v.z * v.z + v.w * v.w;
    #pragma unroll
    for (int off = 32; off; off >>= 1) ss += __shfl_xor(ss, off);
    float rs = rsqrtf(ss * (1.f / D_MODEL) + 1e-5f);
    const float4 wv = *(const float4*)(w + lane * 4);
    bf16x4 ov;
    ov[0] = (bf16_t)(v.x * rs * wv.x);
    ov[1] = (bf16_t)(v.y * rs * wv.y);
    ov[2] = (bf16_t)(v.z * rs * wv.z);
    ov[3] = (bf16_t)(v.w * rs * wv.w);
    *(bf16x4*)(o + (size_t)row * D_MODEL + lane * 4) = ov;
}

// ---------------------------------------------------------------------------
// R23: FUSED W_in GEMM + conv+silu + W_x GEMM + delta precompute.
// One block per 16-token tile (128 blocks). The block computes the W_in
// x-half for its 16 tokens PLUS a 3-token halo (recomputed, ~10% extra MFMA)
// directly into the fp32 xs LDS slab the conv reads -- xz never exists.
// The z-half + silu -> szT epilogue rides the same GEMM. Kills one dispatch
// boundary per layer and the full xz HBM round-trip.
// ---------------------------------------------------------------------------
struct GemmSM { bf16_t As[19][264]; bf16_t Bs[64][264]; };
struct PostSM { bf16_t us[16][520]; f32x4 part[4][3][64]; float dtt[16][17]; };
union FusedSM { GemmSM g; PostSM p; };

__global__ __launch_bounds__(256) void fused_win_conv(
    const bf16_t* __restrict__ A,     // xn_bf (BL, 256)
    const bf16_t* __restrict__ Bw,    // Wi_bf (1024, 256)
    const float* __restrict__ bias,   // (1024)
    const float* __restrict__ cw,     // (512, 4)
    const bf16_t* __restrict__ Wx,    // Wx_bf (48, 512)
    const float* __restrict__ dt_w,   // (512, 16)
    const float* __restrict__ dt_b,   // (512)
    bf16_t* __restrict__ szT,         // (512, BL) bf16
    bf16_t* __restrict__ uT,          // (512, BL) bf16
    float* __restrict__ xdbcT,        // (48, BL)
    float* __restrict__ deltaT)       // (512, BL) fp32 (exp-sensitive)
{
    constexpr int K = 256;            // W_in K
    __shared__ float xs[19][516];     // conv input slab (fp32), persistent
    __shared__ FusedSM sm;

    const int tid  = threadIdx.x;
    const int wave = tid >> 6, lane = tid & 63;
    const int lm = lane & 15, quad = lane >> 4;
    const int m0 = blockIdx.x * 16;

    // ---- stage A: rows m0-3..m0+15 (19), full K; zero rows before t=0 ----
    for (int i = tid; i < 19 * 32; i += 256) {
        int r = i >> 5, c8 = i & 31;
        int mr = m0 - 3 + r;
        bf16x8 v;
        #pragma unroll
        for (int e = 0; e < 8; ++e) v[e] = (bf16_t)0.f;
        if (mr >= 0) v = *(const bf16x8*)(A + (size_t)mr * K + c8 * 8);
        *(bf16x8*)&sm.g.As[r][c8 * 8] = v;
    }

    // ---- W_in GEMM: 16 n-chunks of 64 cols; full-K Bs per chunk ----
    for (int nc = 0; nc < 16; ++nc) {
        #pragma unroll
        for (int i = tid; i < 64 * 32; i += 256) {
            int r = i >> 5, c8 = i & 31;
            *(bf16x8*)&sm.g.Bs[r][c8 * 8] =
                *(const bf16x8*)(Bw + (size_t)(nc * 64 + r) * K + c8 * 8);
        }
        __syncthreads();   // first iteration also covers As staging

        const bool xhalf = (nc < 8);
        f32x4 acc0 = {}, acc1 = {};
        #pragma unroll
        for (int ks = 0; ks < 8; ++ks) {
            bf16x8 bfr = *(const bf16x8*)&sm.g.Bs[wave * 16 + lm][ks * 32 + quad * 8];
            bf16x8 afm = *(const bf16x8*)&sm.g.As[3 + lm][ks * 32 + quad * 8];
            acc0 = __builtin_amdgcn_mfma_f32_16x16x32_bf16(afm, bfr, acc0, 0, 0, 0);
            if (xhalf) {
                bf16x8 afh = *(const bf16x8*)&sm.g.As[lm][ks * 32 + quad * 8];
                acc1 = __builtin_amdgcn_mfma_f32_16x16x32_bf16(afh, bfr, acc1, 0, 0, 0);
            }
        }

        const int col = nc * 64 + wave * 16 + lm;
        const float bj = bias[col];
        if (xhalf) {
            #pragma unroll
            for (int r = 0; r < 4; ++r)
                xs[3 + quad * 4 + r][col] = acc0[r] + bj;
            if (quad == 0) {
                #pragma unroll
                for (int r = 0; r < 3; ++r)
                    xs[r][col] = acc1[r] + bj;   // halo tokens m0-3..m0-1
            }
        } else {
            bf16x4 o;
            #pragma unroll
            for (int r = 0; r < 4; ++r) {
                float v = acc0[r] + bj;
                o[r] = (bf16_t)(v / (1.f + __expf(-v)));
            }
            *(bf16x4*)(szT + (size_t)(col - D_INNER) * BL + m0 + quad * 4) = o;
        }
        __syncthreads();   // Bs reused next chunk; xs writes drained at loop end
    }

    // ---- conv + silu for 512 channels x 16 rows; write uT + us ----
    #pragma unroll
    for (int it = 0; it < 8; ++it) {
        int item = tid + it * 256;
        int d = item >> 2, rg = item & 3;
        const float4 wv = *(const float4*)(cw + d * 4);
        bf16x4 ob;
        #pragma unroll
        for (int e = 0; e < 4; ++e) {
            int ro = rg * 4 + e;
            int t  = (m0 + ro) & (L_SZ - 1);
            float a = wv.w * xs[ro + 3][d];
            if (t >= 1) a += wv.z * xs[ro + 2][d];
            if (t >= 2) a += wv.y * xs[ro + 1][d];
            if (t >= 3) a += wv.x * xs[ro + 0][d];
            a = a / (1.f + __expf(-a));
            ob[e] = (bf16_t)a;
            sm.p.us[ro][d] = (bf16_t)a;
        }
        *(bf16x4*)(uT + (size_t)d * BL + m0 + rg * 4) = ob;
    }
    __syncthreads();

    // ---- W_x GEMM (wave-parallel K-split) ----
    {
        f32x4 acc[3] = {};
        const int kb = wave * 128 + quad * 8;
        #pragma unroll
        for (int ks = 0; ks < 4; ++ks) {
            int k0 = kb + ks * 32;
            bf16x8 af = *(const bf16x8*)&sm.p.us[lm][k0];
            #pragma unroll
            for (int j = 0; j < 3; ++j) {
                bf16x8 bfr = *(const bf16x8*)(Wx + (size_t)(j * 16 + lm) * D_INNER + k0);
                acc[j] = __builtin_amdgcn_mfma_f32_16x16x32_bf16(af, bfr, acc[j], 0, 0, 0);
            }
        }
        #pragma unroll
        for (int j = 0; j < 3; ++j) sm.p.part[wave][j][lane] = acc[j];
    }
    __syncthreads();

    if (tid < 192) {
        int j = tid >> 6, l = tid & 63;
        f32x4 s = sm.p.part[0][j][l];
        s += sm.p.part[1][j][l];
        s += sm.p.part[2][j][l];
        s += sm.p.part[3][j][l];
        int col = j * 16 + (l & 15);
        float4 v = make_float4(s[0], s[1], s[2], s[3]);
        *(float4*)(xdbcT + (size_t)col * BL + m0 + (l >> 4) * 4) = v;
        if (j == 0) {
            #pragma unroll
            for (int e = 0; e < 4; ++e)
                sm.p.dtt[(l >> 4) * 4 + e][l & 15] = s[e];
        }
    }
    __syncthreads();

    // ---- delta = softplus(dt @ dt_w^T + dt_b) for 512 d x 16 tokens ----
    #pragma unroll
    for (int it = 0; it < 8; ++it) {
        int item = tid + it * 256;
        int d = item >> 2, tg = item & 3;
        const float4 w0 = *(const float4*)(dt_w + (size_t)d * 16 + 0);
        const float4 w1 = *(const float4*)(dt_w + (size_t)d * 16 + 4);
        const float4 w2 = *(const float4*)(dt_w + (size_t)d * 16 + 8);
        const float4 w3 = *(const float4*)(dt_w + (size_t)d * 16 + 12);
        const float bdt = dt_b[d];
        float4 o;
        #pragma unroll
        for (int e = 0; e < 4; ++e) {
            int t = tg * 4 + e;
            float a = bdt;
            a += sm.p.dtt[t][0]  * w0.x + sm.p.dtt[t][1]  * w0.y
               + sm.p.dtt[t][2]  * w0.z + sm.p.dtt[t][3]  * w0.w;
            a += sm.p.dtt[t][4]  * w1.x + sm.p.dtt[t][5]  * w1.y
               + sm.p.dtt[t][6]  * w1.z + sm.p.dtt[t][7]  * w1.w;
            a += sm.p.dtt[t][8]  * w2.x + sm.p.dtt[t][9]  * w2.y
               + sm.p.dtt[t][10] * w2.z + sm.p.dtt[t][11] * w2.w;
            a += sm.p.dtt[t][12] * w3.x + sm.p.dtt[t][13] * w3.y
               + sm.p.dtt[t][14] * w3.z + sm.p.dtt[t][15] * w3.w;
            ((float*)&o)[e] = (a > 20.f) ? a : __logf(1.f + __expf(a));
        }
        *(float4*)(deltaT + (size_t)d * BL + m0 + tg * 4) = o;
    }
}

// ---------------------------------------------------------------------------
// W_out GEMM + residual + fused next-layer RMSNorm (R21, unchanged).
// ---------------------------------------------------------------------------
__global__ __launch_bounds__(256) void gemm_wout_norm(
    const bf16_t* __restrict__ A,      // y_bf (BL, 512)
    const bf16_t* __restrict__ Bw,     // Wo_bf (256, 512)
    const float* __restrict__ bias,    // (256)
    const float* __restrict__ R,       // residual xcur (BL, 256)
    const float* __restrict__ nw,      // norm_w of NEXT layer (256)
    float* __restrict__ C,             // out (BL, 256)
    bf16_t* __restrict__ Xn)           // xn_bf (BL, 256) for next layer
{
    constexpr int K = 512, BK = 64, BM = 16, BN = 256, LDK = BK + 8;
    __shared__ bf16_t As[BM][LDK];
    __shared__ bf16_t Bs[BN][LDK];
    __shared__ float rsum[BM][5];

    const int tid  = threadIdx.x;
    const int wave = tid >> 6, lane = tid & 63;
    const int lm = lane & 15, quad = lane >> 4;
    const int m0 = blockIdx.x * BM;

    f32x4 acc[4] = {};
    for (int k0 = 0; k0 < K; k0 += BK) {
        if (tid < BM * (BK / 8)) {
            int r = tid >> 3, c8 = tid & 7;
            *(bf16x8*)&As[r][c8 * 8] =
                *(const bf16x8*)(A + (size_t)(m0 + r) * K + k0 + c8 * 8);
        }
        #pragma unroll
        for (int i = tid; i < BN * (BK / 8); i += 256) {
            int r = i >> 3, c8 = i & 7;
            *(bf16x8*)&Bs[r][c8 * 8] =
                *(const bf16x8*)(Bw + (size_t)r * K + k0 + c8 * 8);
        }
        __syncthreads();
        #pragma unroll
        for (int ks = 0; ks < 2; ++ks) {
            bf16x8 af = *(const bf16x8*)&As[lm][ks * 32 + quad * 8];
            #pragma unroll
            for (int j = 0; j < 4; ++j) {
                bf16x8 bfr = *(const bf16x8*)&Bs[wave * 64 + j * 16 + lm][ks * 32 + quad * 8];
                acc[j] = __builtin_amdgcn_mfma_f32_16x16x32_bf16(af, bfr, acc[j], 0, 0, 0);
            }
        }
        __syncthreads();
    }

    float vv[4][4];
    #pragma unroll
    for (int j = 0; j < 4; ++j) {
        int col = wave * 64 + j * 16 + lm;
        float bj = bias[col];
        #pragma unroll
        for (int r = 0; r < 4; ++r) {
            int row = m0 + quad * 4 + r;
            vv[j][r] = acc[j][r] + bj + R[(size_t)row * D_MODEL + col];
        }
    }
    #pragma unroll
    for (int r = 0; r < 4; ++r) {
        float p = vv[0][r] * vv[0][r] + vv[1][r] * vv[1][r]
                + vv[2][r] * vv[2][r] + vv[3][r] * vv[3][r];
        p = row_allreduce16(p);
        if (lm == 0) rsum[quad * 4 + r][wave] = p;
    }
    __syncthreads();
    float rs[4];
    #pragma unroll
    for (int r = 0; r < 4; ++r) {
        int lr = quad * 4 + r;
        float tot = rsum[lr][0] + rsum[lr][1] + rsum[lr][2] + rsum[lr][3];
        rs[r] = rsqrtf(tot * (1.f / D_MODEL) + 1e-5f);
    }
    #pragma unroll
    for (int j = 0; j < 4; ++j) {
        int col = wave * 64 + j * 16 + lm;
        float wj = nw[col];
        #pragma unroll
        for (int r = 0; r < 4; ++r) {
            int row = m0 + quad * 4 + r;
            C[(size_t)row * D_MODEL + col] = vv[j][r];
            Xn[(size_t)row * D_MODEL + col] = (bf16_t)(vv[j][r] * rs[r] * wj);
        }
    }
}

// ---------------------------------------------------------------------------
// Selective scan v9 (R22 unchanged): bf16 u/sz inputs, fp32 math.
// ---------------------------------------------------------------------------
__global__ __launch_bounds__(1024, 4) void scan_kernel(
    const float* __restrict__ xdbcT,  // (48, BL): [dt | B | C]
    const float* __restrict__ deltaT, // (512, BL) fp32
    const bf16_t* __restrict__ uT,    // (512, BL) bf16
    const bf16_t* __restrict__ szT,   // (512, BL) bf16
    const float* __restrict__ A_log,  // (512, 16)
    const float* __restrict__ Dv,     // (512)
    bf16_t* __restrict__ y)           // (BL, 512) bf16
{
    constexpr int TC = 32;
    constexpr int NW = L_SZ / TC;     // 16 waves

    int blk  = blockIdx.x;            // 512 blocks: b*128 + dg
    int b    = blk >> 7;
    int dg   = blk & 127;
    int wave = threadIdx.x >> 6;
    int lane = threadIdx.x & 63;
    int d    = dg * 4 + (lane >> 4);
    int n    = lane & 15;

    __shared__ float lds_Ap[NW][64];
    __shared__ float lds_he[NW][64];

    float Adn = -__expf(A_log[d * D_STATE + n]);
    int r0 = b * L_SZ + wave * TC;

    const float* Brow  = xdbcT  + (size_t)(DT_RANK + n) * BL;
    const float* Crow  = xdbcT  + (size_t)(DT_RANK + D_STATE + n) * BL;
    const float* drow  = deltaT + (size_t)d * BL;
    const bf16_t* urow = uT     + (size_t)d * BL;
    const bf16_t* zrow = szT    + (size_t)d * BL;

    // ---- pass 1: chunk-end state only (running h and P = prod dA) ----
    {
        float h = 0.f, P = 1.f;
        #pragma unroll
        for (int j4 = 0; j4 < 8; ++j4) {
            int rb = r0 + j4 * 4;
            f32x4 dl = *(const f32x4*)(drow + rb);
            f32x4 Bv = *(const f32x4*)(Brow + rb);
            bf16x4 ub = *(const bf16x4*)(urow + rb);
            #pragma unroll
            for (int k = 0; k < 4; ++k) {
                float dA = __expf(dl[k] * Adn);
                h = dA * h + dl[k] * (float)ub[k] * Bv[k];
                P *= dA;
            }
        }
        lds_Ap[wave][lane] = P;
        lds_he[wave][lane] = h;
    }
    __syncthreads();

    // ---- cross-wave carry: H = state entering this wave's chunk ----
    float H = 0.f;
    for (int j = 0; j < wave; ++j)
        H = lds_Ap[j][lane] * H + lds_he[j][lane];

    // ---- pass 2: re-run recurrence seeded with H; emit y ----
    float Dd = Dv[d];
    float h = H;
    #pragma unroll
    for (int g = 0; g < 2; ++g) {
        float py[16];
        #pragma unroll
        for (int j4 = 0; j4 < 4; ++j4) {
            int rb = r0 + g * 16 + j4 * 4;
            f32x4 dl = *(const f32x4*)(drow + rb);
            f32x4 Bv = *(const f32x4*)(Brow + rb);
            bf16x4 ub = *(const bf16x4*)(urow + rb);
            f32x4 Cc = *(const f32x4*)(Crow + rb);
            #pragma unroll
            for (int k = 0; k < 4; ++k) {
                float dA = __expf(dl[k] * Adn);
                h = dA * h + dl[k] * (float)ub[k] * Bv[k];
                py[j4 * 4 + k] = h * Cc[k];
            }
        }
        #pragma unroll
        for (int j = 0; j < 16; ++j)
            py[j] = row_allreduce16(py[j]);
        if (n == 0) {
            #pragma unroll
            for (int j4 = 0; j4 < 4; ++j4) {
                int rb = r0 + g * 16 + j4 * 4;
                bf16x4 ub = *(const bf16x4*)(urow + rb);
                bf16x4 zb = *(const bf16x4*)(zrow + rb);
                #pragma unroll
                for (int k = 0; k < 4; ++k) {
                    int row = rb + k;
                    y[(size_t)row * D_INNER + d] =
                        (bf16_t)((py[j4*4+k] + (float)ub[k] * Dd) * (float)zb[k]);
                }
            }
        }
    }
}

// ---------------------------------------------------------------------------
extern "C" void kernel_launch(void* const* d_in, const int* in_sizes, int n_in,
                              void* d_out, int out_size, void* d_ws, size_t ws_size,
                              hipStream_t stream)
{
    const float* x_in   = (const float*)d_in[0];
    const float* norm_w = (const float*)d_in[1];
    const float* W_in   = (const float*)d_in[2];
    const float* b_in   = (const float*)d_in[3];
    const float* conv_w = (const float*)d_in[4];
    const float* W_x    = (const float*)d_in[5];
    const float* dt_w   = (const float*)d_in[6];
    const float* dt_b   = (const float*)d_in[7];
    const float* A_log  = (const float*)d_in[8];
    const float* Dv     = (const float*)d_in[9];
    const float* W_out  = (const float*)d_in[10];
    const float* b_out  = (const float*)d_in[11];
    float* out = (float*)d_out;

    // fp32 scratch
    float* ws     = (float*)d_ws;
    float* xdbcT  = ws;                        // 48*2048
    float* deltaT = xdbcT + 48 * BL;           // 512*2048
    // bf16 scratch
    bf16_t* bws   = (bf16_t*)(deltaT + D_INNER * BL);
    bf16_t* uT    = bws;                       // 512*2048
    bf16_t* szT   = uT    + D_INNER * BL;      // 512*2048
    bf16_t* xn_bf = szT   + D_INNER * BL;      // 2048*256
    bf16_t* y_bf  = xn_bf + BL * D_MODEL;      // 2048*512
    bf16_t* Wi_bf = y_bf  + BL * D_INNER;      // 6*1024*256
    bf16_t* Wx_bf = Wi_bf + N_LAYERS * 2 * D_INNER * D_MODEL;
    bf16_t* Wo_bf = Wx_bf + N_LAYERS * 48 * D_INNER;

    // ---- weight casts, one dispatch (dsts contiguous: Wi|Wx|Wo) ----
    {
        int n0 = N_LAYERS * 2 * D_INNER * D_MODEL / 4;
        int n1 = N_LAYERS * 48 * D_INNER / 4;
        int n2 = N_LAYERS * D_MODEL * D_INNER / 4;
        cast3_kernel<<<(n0 + n1 + n2 + 255) / 256, 256, 0, stream>>>(
            W_in, W_x, W_out, Wi_bf, n0, n1, n2);
    }

    // layer 0's norm (reads x_in); later norms fused into gemm_wout_norm
    rmsnorm_kernel<<<BL / 4, 256, 0, stream>>>(x_in, norm_w, xn_bf);

    for (int i = 0; i < N_LAYERS; ++i) {
        const float* xcur = (i == 0) ? x_in : out;

        // fused W_in GEMM + conv + W_x + delta (xz eliminated)
        fused_win_conv<<<BL / 16, 256, 0, stream>>>(
            xn_bf, Wi_bf + (size_t)i * 2 * D_INNER * D_MODEL,
            b_in + i * 2 * D_INNER,
            conv_w + i * D_INNER * 4,
            Wx_bf + (size_t)i * 48 * D_INNER,
            dt_w + (size_t)i * D_INNER * DT_RANK, dt_b + i * D_INNER,
            szT, uT, xdbcT, deltaT);

        // scan v9 (bf16 u/sz inputs)
        scan_kernel<<<512, 1024, 0, stream>>>(
            xdbcT, deltaT, uT, szT,
            A_log + (size_t)i * D_INNER * D_STATE, Dv + i * D_INNER, y_bf);

        // out = xcur + y @ W_out^T + b_out, fused with next layer's rmsnorm
        const float* nw_next = norm_w + (size_t)((i + 1) % N_LAYERS) * D_MODEL;
        gemm_wout_norm<<<BL / 16, 256, 0, stream>>>(
            y_bf, Wo_bf + (size_t)i * D_MODEL * D_INNER,
            b_out + i * D_MODEL, xcur, nw_next, out, xn_bf);
    }
}

// Round 9
// 544.758 us; speedup vs baseline: 1.2231x; 1.2231x over previous
//
#include <hip/hip_runtime.h>
#include <hip/hip_bf16.h>

#define B_SZ 4
#define L_SZ 512
#define D_MODEL 256
#define D_INNER 512
#define D_STATE 16
#define DT_RANK 16
#define N_LAYERS 6
#define BL (B_SZ * L_SZ)   // 2048 token rows

typedef __bf16 bf16_t;
typedef __bf16 bf16x8 __attribute__((ext_vector_type(8)));
typedef __bf16 bf16x4 __attribute__((ext_vector_type(4)));
typedef float  f32x4  __attribute__((ext_vector_type(4)));

// All-reduce over the 16-lane DPP row via rotate-add.
__device__ __forceinline__ float row_allreduce16(float x)
{
    int v;
    v = __builtin_amdgcn_mov_dpp(__float_as_int(x), 0x121, 0xf, 0xf, true);
    x += __int_as_float(v);
    v = __builtin_amdgcn_mov_dpp(__float_as_int(x), 0x122, 0xf, 0xf, true);
    x += __int_as_float(v);
    v = __builtin_amdgcn_mov_dpp(__float_as_int(x), 0x124, 0xf, 0xf, true);
    x += __int_as_float(v);
    v = __builtin_amdgcn_mov_dpp(__float_as_int(x), 0x128, 0xf, 0xf, true);
    x += __int_as_float(v);
    return x;
}

// ---------------------------------------------------------------------------
// R24 prep: layer-0 RMSNorm (blocks 0..511) + weight casts (blocks 512..)
// in ONE dispatch. The two halves are data-independent; norm blocks first so
// xn_bf is ready early while cast blocks keep streaming weights.
// ---------------------------------------------------------------------------
__global__ __launch_bounds__(256) void prep_kernel(
    const float* __restrict__ x, const float* __restrict__ w,
    bf16_t* __restrict__ o,
    const float* __restrict__ s0, const float* __restrict__ s1,
    const float* __restrict__ s2, bf16_t* __restrict__ dst,
    int n0, int n1, int n2)
{
    if (blockIdx.x < BL / 4) {
        // rmsnorm: 4 rows per block, one wave per row of 256
        int row  = blockIdx.x * 4 + (threadIdx.x >> 6);
        int lane = threadIdx.x & 63;
        const float4 v = *(const float4*)(x + (size_t)row * D_MODEL + lane * 4);
        float ss = v.x * v.x + v.y * v.y + v.z * v.z + v.w * v.w;
        #pragma unroll
        for (int off = 32; off; off >>= 1) ss += __shfl_xor(ss, off);
        float rs = rsqrtf(ss * (1.f / D_MODEL) + 1e-5f);
        const float4 wv = *(const float4*)(w + lane * 4);
        bf16x4 ov;
        ov[0] = (bf16_t)(v.x * rs * wv.x);
        ov[1] = (bf16_t)(v.y * rs * wv.y);
        ov[2] = (bf16_t)(v.z * rs * wv.z);
        ov[3] = (bf16_t)(v.w * rs * wv.w);
        *(bf16x4*)(o + (size_t)row * D_MODEL + lane * 4) = ov;
        return;
    }
    int i = (blockIdx.x - BL / 4) * 256 + threadIdx.x;
    const float* s; int off;
    if (i < n0)            { s = s0; off = i; }
    else if (i < n0 + n1)  { s = s1; off = i - n0; }
    else if (i < n0+n1+n2) { s = s2; off = i - n0 - n1; }
    else return;
    const float4 v = *(const float4*)(s + (size_t)off * 4);
    bf16x4 oc;
    oc[0] = (bf16_t)v.x; oc[1] = (bf16_t)v.y;
    oc[2] = (bf16_t)v.z; oc[3] = (bf16_t)v.w;
    *(bf16x4*)(dst + (size_t)i * 4) = oc;
}

// ---------------------------------------------------------------------------
// W_in GEMM (K=256), full-K A staging + ZSPLIT epilogue (R22, unchanged).
// bf16 xz / szT outputs.
// ---------------------------------------------------------------------------
__global__ __launch_bounds__(256) void win_kernel(
    const bf16_t* __restrict__ A,      // xn_bf (BL, 256)
    const bf16_t* __restrict__ Bw,     // Wi_bf (1024, 256)
    const float* __restrict__ bias,    // (1024)
    bf16_t* __restrict__ C,            // xz x-half (BL, 512) bf16
    bf16_t* __restrict__ Z)            // szT (512, BL) bf16
{
    constexpr int K = 256, BK = 64;
    __shared__ bf16_t As[64][K + 8];   // full-K A
    __shared__ bf16_t Bs[64][BK + 8];

    const int tid  = threadIdx.x;
    const int wave = tid >> 6, lane = tid & 63;
    const int wm = wave >> 1, wn = wave & 1;
    const int lm = lane & 15, quad = lane >> 4;
    const int m0 = blockIdx.y * 64, n0 = blockIdx.x * 64;

    #pragma unroll
    for (int i = tid; i < 64 * (K / 8); i += 256) {
        int r = i >> 5, c8 = i & 31;
        *(bf16x8*)&As[r][c8 * 8] =
            *(const bf16x8*)(A + (size_t)(m0 + r) * K + c8 * 8);
    }

    f32x4 acc[2][2] = {};
    for (int k0 = 0; k0 < K; k0 += BK) {
        #pragma unroll
        for (int i = tid; i < 64 * (BK / 8); i += 256) {
            int r = i >> 3, c8 = i & 7;
            *(bf16x8*)&Bs[r][c8 * 8] =
                *(const bf16x8*)(Bw + (size_t)(n0 + r) * K + k0 + c8 * 8);
        }
        __syncthreads();   // first barrier also covers the As staging
        #pragma unroll
        for (int ks = 0; ks < 2; ++ks) {
            bf16x8 af[2], bfr[2];
            #pragma unroll
            for (int i = 0; i < 2; ++i)
                af[i] = *(const bf16x8*)&As[wm * 32 + i * 16 + lm][k0 + ks * 32 + quad * 8];
            #pragma unroll
            for (int j = 0; j < 2; ++j)
                bfr[j] = *(const bf16x8*)&Bs[wn * 32 + j * 16 + lm][ks * 32 + quad * 8];
            #pragma unroll
            for (int i = 0; i < 2; ++i)
                #pragma unroll
                for (int j = 0; j < 2; ++j)
                    acc[i][j] = __builtin_amdgcn_mfma_f32_16x16x32_bf16(
                        af[i], bfr[j], acc[i][j], 0, 0, 0);
        }
        __syncthreads();
    }

    if (n0 >= D_INNER) {
        // z half: bias + silu, transposed bf16x4 stores into Z (d-major)
        #pragma unroll
        for (int i = 0; i < 2; ++i) {
            int rowbase = m0 + wm * 32 + i * 16 + quad * 4;
            #pragma unroll
            for (int j = 0; j < 2; ++j) {
                int col = n0 + wn * 32 + j * 16 + lm;
                bf16x4 o;
                #pragma unroll
                for (int r = 0; r < 4; ++r) {
                    float v = acc[i][j][r] + bias[col];
                    o[r] = (bf16_t)(v / (1.f + __expf(-v)));
                }
                *(bf16x4*)(Z + (size_t)(col - D_INNER) * BL + rowbase) = o;
            }
        }
        return;
    }

    #pragma unroll
    for (int i = 0; i < 2; ++i) {
        #pragma unroll
        for (int j = 0; j < 2; ++j) {
            int col = n0 + wn * 32 + j * 16 + lm;
            #pragma unroll
            for (int r = 0; r < 4; ++r) {
                int rowm = m0 + wm * 32 + i * 16 + quad * 4 + r;
                C[(size_t)rowm * D_INNER + col] = (bf16_t)(acc[i][j][r] + bias[col]);
            }
        }
    }
}

// ---------------------------------------------------------------------------
// W_out GEMM + residual + fused next-layer RMSNorm (R21, unchanged).
// ---------------------------------------------------------------------------
__global__ __launch_bounds__(256) void gemm_wout_norm(
    const bf16_t* __restrict__ A,      // y_bf (BL, 512)
    const bf16_t* __restrict__ Bw,     // Wo_bf (256, 512)
    const float* __restrict__ bias,    // (256)
    const float* __restrict__ R,       // residual xcur (BL, 256)
    const float* __restrict__ nw,      // norm_w of NEXT layer (256)
    float* __restrict__ C,             // out (BL, 256)
    bf16_t* __restrict__ Xn)           // xn_bf (BL, 256) for next layer
{
    constexpr int K = 512, BK = 64, BM = 16, BN = 256, LDK = BK + 8;
    __shared__ bf16_t As[BM][LDK];
    __shared__ bf16_t Bs[BN][LDK];
    __shared__ float rsum[BM][5];

    const int tid  = threadIdx.x;
    const int wave = tid >> 6, lane = tid & 63;
    const int lm = lane & 15, quad = lane >> 4;
    const int m0 = blockIdx.x * BM;

    f32x4 acc[4] = {};
    for (int k0 = 0; k0 < K; k0 += BK) {
        if (tid < BM * (BK / 8)) {
            int r = tid >> 3, c8 = tid & 7;
            *(bf16x8*)&As[r][c8 * 8] =
                *(const bf16x8*)(A + (size_t)(m0 + r) * K + k0 + c8 * 8);
        }
        #pragma unroll
        for (int i = tid; i < BN * (BK / 8); i += 256) {
            int r = i >> 3, c8 = i & 7;
            *(bf16x8*)&Bs[r][c8 * 8] =
                *(const bf16x8*)(Bw + (size_t)r * K + k0 + c8 * 8);
        }
        __syncthreads();
        #pragma unroll
        for (int ks = 0; ks < 2; ++ks) {
            bf16x8 af = *(const bf16x8*)&As[lm][ks * 32 + quad * 8];
            #pragma unroll
            for (int j = 0; j < 4; ++j) {
                bf16x8 bfr = *(const bf16x8*)&Bs[wave * 64 + j * 16 + lm][ks * 32 + quad * 8];
                acc[j] = __builtin_amdgcn_mfma_f32_16x16x32_bf16(af, bfr, acc[j], 0, 0, 0);
            }
        }
        __syncthreads();
    }

    float vv[4][4];
    #pragma unroll
    for (int j = 0; j < 4; ++j) {
        int col = wave * 64 + j * 16 + lm;
        float bj = bias[col];
        #pragma unroll
        for (int r = 0; r < 4; ++r) {
            int row = m0 + quad * 4 + r;
            vv[j][r] = acc[j][r] + bj + R[(size_t)row * D_MODEL + col];
        }
    }
    #pragma unroll
    for (int r = 0; r < 4; ++r) {
        float p = vv[0][r] * vv[0][r] + vv[1][r] * vv[1][r]
                + vv[2][r] * vv[2][r] + vv[3][r] * vv[3][r];
        p = row_allreduce16(p);
        if (lm == 0) rsum[quad * 4 + r][wave] = p;
    }
    __syncthreads();
    float rs[4];
    #pragma unroll
    for (int r = 0; r < 4; ++r) {
        int lr = quad * 4 + r;
        float tot = rsum[lr][0] + rsum[lr][1] + rsum[lr][2] + rsum[lr][3];
        rs[r] = rsqrtf(tot * (1.f / D_MODEL) + 1e-5f);
    }
    #pragma unroll
    for (int j = 0; j < 4; ++j) {
        int col = wave * 64 + j * 16 + lm;
        float wj = nw[col];
        #pragma unroll
        for (int r = 0; r < 4; ++r) {
            int row = m0 + quad * 4 + r;
            C[(size_t)row * D_MODEL + col] = vv[j][r];
            Xn[(size_t)row * D_MODEL + col] = (bf16_t)(vv[j][r] * rs[r] * wj);
        }
    }
}

// ---------------------------------------------------------------------------
// Fused conv+silu + W_x GEMM + delta precompute (R22, unchanged).
// bf16 xz input (fp32 in LDS), bf16 uT output, fp32 deltaT.
// ---------------------------------------------------------------------------
__global__ __launch_bounds__(256) void wx_conv_kernel(
    const bf16_t* __restrict__ xzx,   // (BL, 512) x half, m-major, bf16
    const float* __restrict__ cw,     // (512, 4)
    const bf16_t* __restrict__ Bw,    // Wx_bf (48, 512)
    const float* __restrict__ dt_w,   // (512, 16)
    const float* __restrict__ dt_b,   // (512)
    bf16_t* __restrict__ uT,          // (512, BL) bf16
    float* __restrict__ xdbcT,        // (48, BL)
    float* __restrict__ deltaT)       // (512, BL) fp32 (exp-sensitive)
{
    constexpr int K = 512;
    __shared__ float  xs[19][516];    // xz rows m0-3..m0+15 (fp32 in LDS)
    __shared__ bf16_t us[16][520];    // u tile, [m][k], bf16
    __shared__ f32x4  part[4][3][64];
    __shared__ float  dtt[16][17];    // dt tile, [t][k]

    const int tid  = threadIdx.x;
    const int wave = tid >> 6, lane = tid & 63;
    const int lm = lane & 15, quad = lane >> 4;
    const int m0 = blockIdx.x * 16;

    // stage xs: 19 rows x 64 chunks of 8 bf16 -> fp32 LDS
    for (int q = tid; q < 19 * 64; q += 256) {
        int rx = q >> 6, c8 = (q & 63) * 8;
        int mr = m0 - 3 + rx;
        if (mr >= 0) {
            bf16x8 v = *(const bf16x8*)(xzx + (size_t)mr * K + c8);
            #pragma unroll
            for (int e = 0; e < 8; ++e) xs[rx][c8 + e] = (float)v[e];
        } else {
            #pragma unroll
            for (int e = 0; e < 8; ++e) xs[rx][c8 + e] = 0.f;
        }
    }
    __syncthreads();

    #pragma unroll
    for (int it = 0; it < 8; ++it) {
        int item = tid + it * 256;
        int d = item >> 2, rg = item & 3;
        const float4 wv = *(const float4*)(cw + d * 4);
        bf16x4 ob;
        #pragma unroll
        for (int e = 0; e < 4; ++e) {
            int ro = rg * 4 + e;
            int t  = (m0 + ro) & (L_SZ - 1);
            float a = wv.w * xs[ro + 3][d];
            if (t >= 1) a += wv.z * xs[ro + 2][d];
            if (t >= 2) a += wv.y * xs[ro + 1][d];
            if (t >= 3) a += wv.x * xs[ro + 0][d];
            a = a / (1.f + __expf(-a));
            ob[e] = (bf16_t)a;
            us[ro][d] = (bf16_t)a;
        }
        *(bf16x4*)(uT + (size_t)d * BL + m0 + rg * 4) = ob;
    }
    __syncthreads();

    f32x4 acc[3] = {};
    const int kb = wave * 128 + quad * 8;
    #pragma unroll
    for (int ks = 0; ks < 4; ++ks) {
        int k0 = kb + ks * 32;
        bf16x8 af = *(const bf16x8*)&us[lm][k0];
        #pragma unroll
        for (int j = 0; j < 3; ++j) {
            bf16x8 bfr = *(const bf16x8*)(Bw + (size_t)(j * 16 + lm) * K + k0);
            acc[j] = __builtin_amdgcn_mfma_f32_16x16x32_bf16(af, bfr, acc[j], 0, 0, 0);
        }
    }
    #pragma unroll
    for (int j = 0; j < 3; ++j) part[wave][j][lane] = acc[j];
    __syncthreads();

    if (tid < 192) {
        int j = tid >> 6, l = tid & 63;
        f32x4 s = part[0][j][l];
        s += part[1][j][l];
        s += part[2][j][l];
        s += part[3][j][l];
        int col = j * 16 + (l & 15);
        float4 v = make_float4(s[0], s[1], s[2], s[3]);
        *(float4*)(xdbcT + (size_t)col * BL + m0 + (l >> 4) * 4) = v;
        if (j == 0) {
            #pragma unroll
            for (int e = 0; e < 4; ++e)
                dtt[(l >> 4) * 4 + e][l & 15] = s[e];
        }
    }
    __syncthreads();

    // ---- delta = softplus(dt @ dt_w^T + dt_b) for 512 d x 16 tokens ----
    #pragma unroll
    for (int it = 0; it < 8; ++it) {
        int item = tid + it * 256;
        int d = item >> 2, tg = item & 3;
        const float4 w0 = *(const float4*)(dt_w + (size_t)d * 16 + 0);
        const float4 w1 = *(const float4*)(dt_w + (size_t)d * 16 + 4);
        const float4 w2 = *(const float4*)(dt_w + (size_t)d * 16 + 8);
        const float4 w3 = *(const float4*)(dt_w + (size_t)d * 16 + 12);
        const float bdt = dt_b[d];
        float4 o;
        #pragma unroll
        for (int e = 0; e < 4; ++e) {
            int t = tg * 4 + e;
            float a = bdt;
            a += dtt[t][0]  * w0.x + dtt[t][1]  * w0.y + dtt[t][2]  * w0.z + dtt[t][3]  * w0.w;
            a += dtt[t][4]  * w1.x + dtt[t][5]  * w1.y + dtt[t][6]  * w1.z + dtt[t][7]  * w1.w;
            a += dtt[t][8]  * w2.x + dtt[t][9]  * w2.y + dtt[t][10] * w2.z + dtt[t][11] * w2.w;
            a += dtt[t][12] * w3.x + dtt[t][13] * w3.y + dtt[t][14] * w3.z + dtt[t][15] * w3.w;
            ((float*)&o)[e] = (a > 20.f) ? a : __logf(1.f + __expf(a));
        }
        *(float4*)(deltaT + (size_t)d * BL + m0 + tg * 4) = o;
    }
}

// ---------------------------------------------------------------------------
// Selective scan v9 (R22, unchanged): bf16 u/sz inputs, fp32 math.
// ---------------------------------------------------------------------------
__global__ __launch_bounds__(1024, 4) void scan_kernel(
    const float* __restrict__ xdbcT,  // (48, BL): [dt | B | C]
    const float* __restrict__ deltaT, // (512, BL) fp32
    const bf16_t* __restrict__ uT,    // (512, BL) bf16
    const bf16_t* __restrict__ szT,   // (512, BL) bf16
    const float* __restrict__ A_log,  // (512, 16)
    const float* __restrict__ Dv,     // (512)
    bf16_t* __restrict__ y)           // (BL, 512) bf16
{
    constexpr int TC = 32;
    constexpr int NW = L_SZ / TC;     // 16 waves

    int blk  = blockIdx.x;            // 512 blocks: b*128 + dg
    int b    = blk >> 7;
    int dg   = blk & 127;
    int wave = threadIdx.x >> 6;
    int lane = threadIdx.x & 63;
    int d    = dg * 4 + (lane >> 4);
    int n    = lane & 15;

    __shared__ float lds_Ap[NW][64];
    __shared__ float lds_he[NW][64];

    float Adn = -__expf(A_log[d * D_STATE + n]);
    int r0 = b * L_SZ + wave * TC;

    const float* Brow  = xdbcT  + (size_t)(DT_RANK + n) * BL;
    const float* Crow  = xdbcT  + (size_t)(DT_RANK + D_STATE + n) * BL;
    const float* drow  = deltaT + (size_t)d * BL;
    const bf16_t* urow = uT     + (size_t)d * BL;
    const bf16_t* zrow = szT    + (size_t)d * BL;

    // ---- pass 1: chunk-end state only (running h and P = prod dA) ----
    {
        float h = 0.f, P = 1.f;
        #pragma unroll
        for (int j4 = 0; j4 < 8; ++j4) {
            int rb = r0 + j4 * 4;
            f32x4 dl = *(const f32x4*)(drow + rb);
            f32x4 Bv = *(const f32x4*)(Brow + rb);
            bf16x4 ub = *(const bf16x4*)(urow + rb);
            #pragma unroll
            for (int k = 0; k < 4; ++k) {
                float dA = __expf(dl[k] * Adn);
                h = dA * h + dl[k] * (float)ub[k] * Bv[k];
                P *= dA;
            }
        }
        lds_Ap[wave][lane] = P;
        lds_he[wave][lane] = h;
    }
    __syncthreads();

    // ---- cross-wave carry: H = state entering this wave's chunk ----
    float H = 0.f;
    for (int j = 0; j < wave; ++j)
        H = lds_Ap[j][lane] * H + lds_he[j][lane];

    // ---- pass 2: re-run recurrence seeded with H; emit y ----
    float Dd = Dv[d];
    float h = H;
    #pragma unroll
    for (int g = 0; g < 2; ++g) {
        float py[16];
        #pragma unroll
        for (int j4 = 0; j4 < 4; ++j4) {
            int rb = r0 + g * 16 + j4 * 4;
            f32x4 dl = *(const f32x4*)(drow + rb);
            f32x4 Bv = *(const f32x4*)(Brow + rb);
            bf16x4 ub = *(const bf16x4*)(urow + rb);
            f32x4 Cc = *(const f32x4*)(Crow + rb);
            #pragma unroll
            for (int k = 0; k < 4; ++k) {
                float dA = __expf(dl[k] * Adn);
                h = dA * h + dl[k] * (float)ub[k] * Bv[k];
                py[j4 * 4 + k] = h * Cc[k];
            }
        }
        #pragma unroll
        for (int j = 0; j < 16; ++j)
            py[j] = row_allreduce16(py[j]);
        if (n == 0) {
            #pragma unroll
            for (int j4 = 0; j4 < 4; ++j4) {
                int rb = r0 + g * 16 + j4 * 4;
                bf16x4 ub = *(const bf16x4*)(urow + rb);
                bf16x4 zb = *(const bf16x4*)(zrow + rb);
                #pragma unroll
                for (int k = 0; k < 4; ++k) {
                    int row = rb + k;
                    y[(size_t)row * D_INNER + d] =
                        (bf16_t)((py[j4*4+k] + (float)ub[k] * Dd) * (float)zb[k]);
                }
            }
        }
    }
}

// ---------------------------------------------------------------------------
extern "C" void kernel_launch(void* const* d_in, const int* in_sizes, int n_in,
                              void* d_out, int out_size, void* d_ws, size_t ws_size,
                              hipStream_t stream)
{
    const float* x_in   = (const float*)d_in[0];
    const float* norm_w = (const float*)d_in[1];
    const float* W_in   = (const float*)d_in[2];
    const float* b_in   = (const float*)d_in[3];
    const float* conv_w = (const float*)d_in[4];
    const float* W_x    = (const float*)d_in[5];
    const float* dt_w   = (const float*)d_in[6];
    const float* dt_b   = (const float*)d_in[7];
    const float* A_log  = (const float*)d_in[8];
    const float* Dv     = (const float*)d_in[9];
    const float* W_out  = (const float*)d_in[10];
    const float* b_out  = (const float*)d_in[11];
    float* out = (float*)d_out;

    // fp32 scratch
    float* ws     = (float*)d_ws;
    float* xdbcT  = ws;                        // 48*2048
    float* deltaT = xdbcT + 48 * BL;           // 512*2048
    // bf16 scratch
    bf16_t* bws   = (bf16_t*)(deltaT + D_INNER * BL);
    bf16_t* xz    = bws;                       // 2048*512 (x half, bf16)
    bf16_t* uT    = xz    + BL * D_INNER;      // 512*2048
    bf16_t* szT   = uT    + D_INNER * BL;      // 512*2048
    bf16_t* xn_bf = szT   + D_INNER * BL;      // 2048*256
    bf16_t* y_bf  = xn_bf + BL * D_MODEL;      // 2048*512
    bf16_t* Wi_bf = y_bf  + BL * D_INNER;      // 6*1024*256
    bf16_t* Wx_bf = Wi_bf + N_LAYERS * 2 * D_INNER * D_MODEL;
    bf16_t* Wo_bf = Wx_bf + N_LAYERS * 48 * D_INNER;

    // ---- prep: layer-0 rmsnorm + weight casts in ONE dispatch ----
    {
        int n0 = N_LAYERS * 2 * D_INNER * D_MODEL / 4;
        int n1 = N_LAYERS * 48 * D_INNER / 4;
        int n2 = N_LAYERS * D_MODEL * D_INNER / 4;
        int cast_blocks = (n0 + n1 + n2 + 255) / 256;
        prep_kernel<<<BL / 4 + cast_blocks, 256, 0, stream>>>(
            x_in, norm_w, xn_bf,
            W_in, W_x, W_out, Wi_bf, n0, n1, n2);
    }

    for (int i = 0; i < N_LAYERS; ++i) {
        const float* xcur = (i == 0) ? x_in : out;

        // xz(x half, bf16) + szT(z half, silu, transposed, bf16)
        win_kernel<<<dim3(1024 / 64, 2048 / 64), 256, 0, stream>>>(
            xn_bf, Wi_bf + (size_t)i * 2 * D_INNER * D_MODEL,
            b_in + i * 2 * D_INNER, xz, szT);

        // conv+silu fused with W_x GEMM + delta precompute
        wx_conv_kernel<<<BL / 16, 256, 0, stream>>>(
            xz, conv_w + i * D_INNER * 4,
            Wx_bf + (size_t)i * 48 * D_INNER,
            dt_w + (size_t)i * D_INNER * DT_RANK, dt_b + i * D_INNER,
            uT, xdbcT, deltaT);

        // scan v9 (bf16 u/sz inputs)
        scan_kernel<<<512, 1024, 0, stream>>>(
            xdbcT, deltaT, uT, szT,
            A_log + (size_t)i * D_INNER * D_STATE, Dv + i * D_INNER, y_bf);

        // out = xcur + y @ W_out^T + b_out, fused with next layer's rmsnorm
        const float* nw_next = norm_w + (size_t)((i + 1) % N_LAYERS) * D_MODEL;
        gemm_wout_norm<<<BL / 16, 256, 0, stream>>>(
            y_bf, Wo_bf + (size_t)i * D_MODEL * D_INNER,
            b_out + i * D_MODEL, xcur, nw_next, out, xn_bf);
    }
}